// Round 13
// baseline (76.596 us; speedup 1.0000x reference)
//
#include <hip/hip_runtime.h>

// out = A @ ( d[:,None] * (B @ h_a) + h_b )
//   h_a = relu(x_a @ W_a + b_a), h_b = relu(x_b @ W_b + b_b)
//   A = scatter(edge_ab) [Na,Nb], B = scatter(edge_ba) [Nb,Na]
//   deg = colcount(A) + rowcount(B); d = 1/deg (0 where deg==0)
// 4-kernel pipeline:
//   K1 w_prep:     zero counters + W -> MFMA fragment layout
//   K2 edges_gemm: fat kernel = {MFMA projection, 1 wave = 16-row tile, full K,
//                  NO LDS / NO syncthreads, bf16 h out} U {edge bucketize}
//   K3 gather_u:   u = d * (B @ h_a_bf16) + h_b_bf16  -> u stored bf16
//   K4 gather_out: out = A @ u_bf16                   -> f32 output
// Buckets ushort (cols < 4096), capacity 256/row. Gathers 16-deep unrolled.

#define D_FEAT 128
#define F_IN 512
#define BCAP 256
#define NROW 4096
#define NGEMMBLK 128   // 512 tiles / 4 waves per block

using short8 = __attribute__((ext_vector_type(8))) short;
using f32x4  = __attribute__((ext_vector_type(4))) float;

struct Params {
    const float* xa; const float* Wa; const float* ba;
    const float* xb; const float* Wb; const float* bb;
    const int* ab_row; const int* ab_col;
    const int* ba_row; const int* ba_col;
    short* WfA; short* WfB;
    unsigned short* ha_bf;   // [Na][128] bf16
    unsigned short* hb_bf;   // [Nb][128] bf16
    unsigned* u_bf;          // [Nb][64]  2x bf16 per word
    int* cnt_ab; int* cnt_ba; int* degc;   // contiguous, zeroed in K1
    unsigned short* buck_ab; unsigned short* buck_ba;
    float* out;
    int Eab; int Eba;
};

__device__ inline unsigned short f2bf(float f) {
    unsigned u = __builtin_bit_cast(unsigned, f);
    unsigned r = (u + 0x7FFFu + ((u >> 16) & 1u)) >> 16;
    return (unsigned short)r;
}
__device__ inline float bf2f(unsigned short s) {
    unsigned u = ((unsigned)s) << 16;
    return __builtin_bit_cast(float, u);
}

// ---- K1: W pre-swizzle into MFMA B-fragment layout + counter zero ---------
//   Wf[t][c][lane][e]: k = t*32 + (lane>>4)*8 + e, col = c*16 + (lane&15)
__global__ __launch_bounds__(256) void w_prep_k(Params P) {
    int g = blockIdx.x * 256 + threadIdx.x;  // 0..16383
    for (int z = g; z < 3 * NROW; z += 16384) P.cnt_ab[z] = 0;
    const float* W = (g < 8192) ? P.Wa : P.Wb;
    short* Wf = (g < 8192) ? P.WfA : P.WfB;
    int i = g & 8191;
    int l = i & 63;
    int c = (i >> 6) & 7;
    int t = i >> 9;  // 0..15
    int col = c * 16 + (l & 15);
    int kbase = t * 32 + (l >> 4) * 8;
    short8 o;
#pragma unroll
    for (int e = 0; e < 8; ++e) o[e] = (short)f2bf(W[(size_t)(kbase + e) * D_FEAT + col]);
    *(short8*)(Wf + (size_t)i * 8) = o;
}

// ---- K2: fat kernel = MFMA GEMM (1 wave / 16-row tile, full K) + bucketize --
__global__ __launch_bounds__(256) void edges_gemm_k(Params P) {
    int blk = blockIdx.x;
    if (blk >= NGEMMBLK) {
        // ---- edge bucketize half: 512 edges/block ----
        int base = (blk - NGEMMBLK) * 512 + threadIdx.x;
#pragma unroll
        for (int q = 0; q < 2; ++q) {
            int g = base + q * 256;
            if (g < P.Eab) {
                int r = P.ab_row[g], c = P.ab_col[g];
                int p = atomicAdd(&P.cnt_ab[r], 1);
                if (p < BCAP) P.buck_ab[(size_t)r * BCAP + p] = (unsigned short)c;
                atomicAdd(&P.degc[c], 1);
            } else if (g < P.Eab + P.Eba) {
                int e = g - P.Eab;
                int r = P.ba_row[e], c = P.ba_col[e];
                int p = atomicAdd(&P.cnt_ba[r], 1);
                if (p < BCAP) P.buck_ba[(size_t)r * BCAP + p] = (unsigned short)c;
            }
        }
        return;
    }
    // ---- MFMA projection half: one wave owns one 16-row tile, all K=512 ----
    const int wid = blk * 4 + (threadIdx.x >> 6);   // 0..511 global wave id
    const int l = threadIdx.x & 63;
    const bool isA = (wid < 256);
    const float* x;  const short* Wf;  const float* bias;  unsigned short* h;
    int tile;
    if (isA) { x = P.xa; Wf = P.WfA; bias = P.ba; h = P.ha_bf; tile = wid; }
    else     { x = P.xb; Wf = P.WfB; bias = P.bb; h = P.hb_bf; tile = wid - 256; }
    const int row0 = tile * 16;
    const int lr = l & 15;   // A-row / C-col within tile
    const int lk = l >> 4;   // k-subgroup / C-row-group

    f32x4 acc[8];
#pragma unroll
    for (int c = 0; c < 8; ++c) acc[c] = (f32x4){0.f, 0.f, 0.f, 0.f};

    const float* xrow = x + (size_t)(row0 + lr) * F_IN + lk * 8;
#pragma unroll 4
    for (int t = 0; t < 16; ++t) {
        float4 xf0 = *(const float4*)(xrow + t * 32);
        float4 xf1 = *(const float4*)(xrow + t * 32 + 4);
        short8 afr;
        afr[0] = (short)f2bf(xf0.x); afr[1] = (short)f2bf(xf0.y);
        afr[2] = (short)f2bf(xf0.z); afr[3] = (short)f2bf(xf0.w);
        afr[4] = (short)f2bf(xf1.x); afr[5] = (short)f2bf(xf1.y);
        afr[6] = (short)f2bf(xf1.z); afr[7] = (short)f2bf(xf1.w);
        const short8* wfp = (const short8*)Wf + ((size_t)t * 8 * 64 + l);
#pragma unroll
        for (int c = 0; c < 8; ++c) {
            short8 bfr = wfp[c * 64];
            acc[c] = __builtin_amdgcn_mfma_f32_16x16x32_bf16(afr, bfr, acc[c], 0, 0, 0);
        }
    }

    // epilogue: bias + relu + bf16, direct stores.
    // C/D map (16x16x32): col = lane&15 -> our output col c*16+lr uses lr as
    // the MFMA col; row = (lane>>4)*4 + reg -> row0 + lk*4 + r.
#pragma unroll
    for (int c = 0; c < 8; ++c) {
        float bv = bias[c * 16 + lr];
#pragma unroll
        for (int r = 0; r < 4; ++r) {
            float v = fmaxf(acc[c][r] + bv, 0.0f);
            h[(size_t)(row0 + lk * 4 + r) * D_FEAT + c * 16 + lr] = f2bf(v);
        }
    }
}

// 16 bf16-pair gathers accumulated into (ax, ay)
#define GATHER8(CBASE)                                                        \
    {                                                                         \
        int c0 = cols[CBASE],     c1 = cols[CBASE + 1];                       \
        int c2 = cols[CBASE + 2], c3 = cols[CBASE + 3];                       \
        int c4 = cols[CBASE + 4], c5 = cols[CBASE + 5];                       \
        int c6 = cols[CBASE + 6], c7 = cols[CBASE + 7];                       \
        unsigned v0 = s2[(size_t)c0 * 64 + lane];                             \
        unsigned v1 = s2[(size_t)c1 * 64 + lane];                             \
        unsigned v2 = s2[(size_t)c2 * 64 + lane];                             \
        unsigned v3 = s2[(size_t)c3 * 64 + lane];                             \
        unsigned v4 = s2[(size_t)c4 * 64 + lane];                             \
        unsigned v5 = s2[(size_t)c5 * 64 + lane];                             \
        unsigned v6 = s2[(size_t)c6 * 64 + lane];                             \
        unsigned v7 = s2[(size_t)c7 * 64 + lane];                             \
        ax += (bf2f((unsigned short)v0) + bf2f((unsigned short)v1)) +         \
              (bf2f((unsigned short)v2) + bf2f((unsigned short)v3)) +         \
              ((bf2f((unsigned short)v4) + bf2f((unsigned short)v5)) +        \
               (bf2f((unsigned short)v6) + bf2f((unsigned short)v7)));        \
        ay += (bf2f((unsigned short)(v0 >> 16)) + bf2f((unsigned short)(v1 >> 16))) + \
              (bf2f((unsigned short)(v2 >> 16)) + bf2f((unsigned short)(v3 >> 16))) + \
              ((bf2f((unsigned short)(v4 >> 16)) + bf2f((unsigned short)(v5 >> 16))) + \
               (bf2f((unsigned short)(v6 >> 16)) + bf2f((unsigned short)(v7 >> 16)))); \
    }

// ---- K3: u[r] = (1/deg[r] or 0) * sum_{c in B-row r} ha_bf[c] + hb_bf[r] --
__global__ __launch_bounds__(256) void gather_u_k(Params P) {
    int r = blockIdx.x * 4 + (threadIdx.x >> 6);
    if (r >= NROW) return;
    int lane = threadIdx.x & 63;
    int ncb = P.cnt_ba[r];                 // true B-row degree
    int dgc = P.degc[r];                   // in flight with gathers
    unsigned hbw = ((const unsigned*)P.hb_bf)[(size_t)r * 64 + lane];  // in flight
    int n = ncb > BCAP ? BCAP : ncb;
    const unsigned short* cols = P.buck_ba + (size_t)r * BCAP;
    const unsigned* s2 = (const unsigned*)P.ha_bf;  // 2 bf16 per unsigned
    float ax = 0.0f, ay = 0.0f;
    int e = 0;
    for (; e + 15 < n; e += 16) { GATHER8(e) GATHER8(e + 8) }
    for (; e + 3 < n; e += 4) {
        int c0 = cols[e], c1 = cols[e + 1], c2 = cols[e + 2], c3 = cols[e + 3];
        unsigned v0 = s2[(size_t)c0 * 64 + lane];
        unsigned v1 = s2[(size_t)c1 * 64 + lane];
        unsigned v2 = s2[(size_t)c2 * 64 + lane];
        unsigned v3 = s2[(size_t)c3 * 64 + lane];
        ax += (bf2f((unsigned short)v0) + bf2f((unsigned short)v1)) +
              (bf2f((unsigned short)v2) + bf2f((unsigned short)v3));
        ay += (bf2f((unsigned short)(v0 >> 16)) + bf2f((unsigned short)(v1 >> 16))) +
              (bf2f((unsigned short)(v2 >> 16)) + bf2f((unsigned short)(v3 >> 16)));
    }
    for (; e < n; ++e) {
        unsigned v = s2[(size_t)cols[e] * 64 + lane];
        ax += bf2f((unsigned short)v);
        ay += bf2f((unsigned short)(v >> 16));
    }
    float dgf = (float)(dgc + ncb);
    float inv = dgf > 0.0f ? 1.0f / dgf : 0.0f;
    float ux = ax * inv + bf2f((unsigned short)hbw);
    float uy = ay * inv + bf2f((unsigned short)(hbw >> 16));
    P.u_bf[(size_t)r * 64 + lane] = (unsigned)f2bf(ux) | ((unsigned)f2bf(uy) << 16);
}

// ---- K4: out[r] = sum_{c in A-row r} u_bf[c]  (f32 output) ----------------
__global__ __launch_bounds__(256) void gather_out_k(Params P) {
    int r = blockIdx.x * 4 + (threadIdx.x >> 6);
    if (r >= NROW) return;
    int lane = threadIdx.x & 63;
    int n = P.cnt_ab[r];
    if (n > BCAP) n = BCAP;
    const unsigned short* cols = P.buck_ab + (size_t)r * BCAP;
    const unsigned* s2 = P.u_bf;
    float ax = 0.0f, ay = 0.0f;
    int e = 0;
    for (; e + 15 < n; e += 16) { GATHER8(e) GATHER8(e + 8) }
    for (; e + 3 < n; e += 4) {
        int c0 = cols[e], c1 = cols[e + 1], c2 = cols[e + 2], c3 = cols[e + 3];
        unsigned v0 = s2[(size_t)c0 * 64 + lane];
        unsigned v1 = s2[(size_t)c1 * 64 + lane];
        unsigned v2 = s2[(size_t)c2 * 64 + lane];
        unsigned v3 = s2[(size_t)c3 * 64 + lane];
        ax += (bf2f((unsigned short)v0) + bf2f((unsigned short)v1)) +
              (bf2f((unsigned short)v2) + bf2f((unsigned short)v3));
        ay += (bf2f((unsigned short)(v0 >> 16)) + bf2f((unsigned short)(v1 >> 16))) +
              (bf2f((unsigned short)(v2 >> 16)) + bf2f((unsigned short)(v3 >> 16)));
    }
    for (; e < n; ++e) {
        unsigned v = s2[(size_t)cols[e] * 64 + lane];
        ax += bf2f((unsigned short)v);
        ay += bf2f((unsigned short)(v >> 16));
    }
    float2 o; o.x = ax; o.y = ay;
    ((float2*)P.out)[(size_t)r * 64 + lane] = o;
}

extern "C" void kernel_launch(void* const* d_in, const int* in_sizes, int n_in,
                              void* d_out, int out_size, void* d_ws, size_t ws_size,
                              hipStream_t stream) {
    const float* x_a = (const float*)d_in[0];
    const float* x_b = (const float*)d_in[1];
    const float* W_a = (const float*)d_in[2];
    const float* b_a = (const float*)d_in[3];
    const float* W_b = (const float*)d_in[4];
    const float* b_b = (const float*)d_in[5];
    const int* ei_ab = (const int*)d_in[6];
    const int* ei_ba = (const int*)d_in[7];

    const int D = in_sizes[3];            // 128
    const int Fa = in_sizes[2] / D;       // 512
    const int Na = in_sizes[0] / Fa;      // 4096
    const int Fb = in_sizes[4] / D;       // 512
    const int Nb = in_sizes[1] / Fb;      // 4096
    const int Eab = in_sizes[6] / 2;      // 131072
    const int Eba = in_sizes[7] / 2;      // 131072

    // ---- workspace layout ----
    char* p = (char*)d_ws;
    unsigned short* ha_bf = (unsigned short*)p; p += (size_t)Na * D * 2;       // 1 MB
    unsigned short* hb_bf = (unsigned short*)p; p += (size_t)Nb * D * 2;       // 1 MB
    unsigned* u_bf = (unsigned*)p; p += (size_t)Nb * (D / 2) * 4;              // 1 MB
    unsigned short* buck_ab = (unsigned short*)p; p += (size_t)Na * BCAP * 2;  // 2 MB
    unsigned short* buck_ba = (unsigned short*)p; p += (size_t)Nb * BCAP * 2;  // 2 MB
    short* WfA = (short*)p; p += (size_t)Fa * D * 2;                           // 128 KB
    short* WfB = (short*)p; p += (size_t)Fb * D * 2;
    int* cnt_ab = (int*)p; p += (size_t)Na * 4;                                // zeroed in K1
    int* cnt_ba = (int*)p; p += (size_t)Nb * 4;
    int* degc   = (int*)p; p += (size_t)Nb * 4;

    Params P;
    P.xa = x_a; P.Wa = W_a; P.ba = b_a;
    P.xb = x_b; P.Wb = W_b; P.bb = b_b;
    P.ab_row = ei_ab; P.ab_col = ei_ab + Eab;
    P.ba_row = ei_ba; P.ba_col = ei_ba + Eba;
    P.WfA = WfA; P.WfB = WfB;
    P.ha_bf = ha_bf; P.hb_bf = hb_bf; P.u_bf = u_bf;
    P.cnt_ab = cnt_ab; P.cnt_ba = cnt_ba; P.degc = degc;
    P.buck_ab = buck_ab; P.buck_ba = buck_ba;
    P.out = (float*)d_out;
    P.Eab = Eab; P.Eba = Eba;

    // K1: zero counters + W -> fragment layout
    w_prep_k<<<64, 256, 0, stream>>>(P);

    // K2: fat kernel — GEMM (blocks 0..127, 4 indep waves each) + bucketize
    int nEdgeBlk = (Eab + Eba + 511) / 512;         // 512
    edges_gemm_k<<<NGEMMBLK + nEdgeBlk, 256, 0, stream>>>(P);

    // K3: u = d * (B @ h_a) + h_b   (bf16 out)
    gather_u_k<<<(Nb + 3) / 4, 256, 0, stream>>>(P);

    // K4: out = A @ u
    gather_out_k<<<(Na + 3) / 4, 256, 0, stream>>>(P);
}

// Round 14
// 46.633 us; speedup vs baseline: 1.6425x; 1.6425x over previous
//
#include <hip/hip_runtime.h>

// out = A @ ( d[:,None] * (B @ h_a) + h_b )
//   h_a = relu(x_a @ W_a + b_a), h_b = relu(x_b @ W_b + b_b)
//   A = scatter(edge_ab) [Na,Nb], B = scatter(edge_ba) [Nb,Na]
//   deg = colcount(A) + rowcount(B); d = 1/deg (0 where deg==0)
// 4-kernel pipeline (round-12 optimum, reverted from the round-13 regression:
// 1-wave-full-K GEMM collapsed TLP -> MfmaUtil 0.6%, 4x slower. K-split wins).
//   K1 w_prep:     zero counters + W -> MFMA fragment layout
//   K2 edges_gemm: fat kernel = {dual MFMA projection, 4-wave K-split + LDS
//                  reduce} U {edge bucketize}
//   K3 gather_u:   u = d * (B @ h_a_bf16) + h_b   -> u stored bf16
//   K4 gather_out: out = A @ u_bf16               -> f32 output
// Buckets ushort (cols < 4096), capacity 256/row. Gathers 16-deep unrolled.

#define D_FEAT 128
#define F_IN 512
#define BCAP 256
#define NROW 4096

using short8 = __attribute__((ext_vector_type(8))) short;
using ushort4v = __attribute__((ext_vector_type(4))) unsigned short;
using f32x4  = __attribute__((ext_vector_type(4))) float;

struct Params {
    const float* xa; const float* Wa; const float* ba;
    const float* xb; const float* Wb; const float* bb;
    const int* ab_row; const int* ab_col;
    const int* ba_row; const int* ba_col;
    short* WfA; short* WfB;
    unsigned short* ha_bf;   // [Na][128] bf16
    float* hb;               // [Nb][128] f32
    unsigned* u_bf;          // [Nb][64]  2x bf16 per word
    int* cnt_ab; int* cnt_ba; int* degc;   // contiguous, zeroed in K1
    unsigned short* buck_ab; unsigned short* buck_ba;
    float* out;
    int Eab; int Eba;
};

__device__ inline unsigned short f2bf(float f) {
    unsigned u = __builtin_bit_cast(unsigned, f);
    unsigned r = (u + 0x7FFFu + ((u >> 16) & 1u)) >> 16;
    return (unsigned short)r;
}
__device__ inline float bf2f(unsigned short s) {
    unsigned u = ((unsigned)s) << 16;
    return __builtin_bit_cast(float, u);
}

// ---- K1: W pre-swizzle into MFMA B-fragment layout + counter zero ---------
//   Wf[t][c][lane][e]: k = t*32 + (lane>>4)*8 + e, col = c*16 + (lane&15)
__global__ __launch_bounds__(256) void w_prep_k(Params P) {
    int g = blockIdx.x * 256 + threadIdx.x;  // 0..16383
    for (int z = g; z < 3 * NROW; z += 16384) P.cnt_ab[z] = 0;
    const float* W = (g < 8192) ? P.Wa : P.Wb;
    short* Wf = (g < 8192) ? P.WfA : P.WfB;
    int i = g & 8191;
    int l = i & 63;
    int c = (i >> 6) & 7;
    int t = i >> 9;  // 0..15
    int col = c * 16 + (l & 15);
    int kbase = t * 32 + (l >> 4) * 8;
    short8 o;
#pragma unroll
    for (int e = 0; e < 8; ++e) o[e] = (short)f2bf(W[(size_t)(kbase + e) * D_FEAT + col]);
    *(short8*)(Wf + (size_t)i * 8) = o;
}

// ---- K2: fat kernel = dual MFMA GEMM (4-wave K-split) + edge bucketize ----
__global__ __launch_bounds__(256) void edges_gemm_k(Params P, int nblk_g) {
    int blk = blockIdx.x;
    if (blk >= nblk_g) {
        // ---- edge bucketize half: 512 edges/block ----
        int base = (blk - nblk_g) * 512 + threadIdx.x;
#pragma unroll
        for (int q = 0; q < 2; ++q) {
            int g = base + q * 256;
            if (g < P.Eab) {
                int r = P.ab_row[g], c = P.ab_col[g];
                int p = atomicAdd(&P.cnt_ab[r], 1);
                if (p < BCAP) P.buck_ab[(size_t)r * BCAP + p] = (unsigned short)c;
                atomicAdd(&P.degc[c], 1);
            } else if (g < P.Eab + P.Eba) {
                int e = g - P.Eab;
                int r = P.ba_row[e], c = P.ba_col[e];
                int p = atomicAdd(&P.cnt_ba[r], 1);
                if (p < BCAP) P.buck_ba[(size_t)r * BCAP + p] = (unsigned short)c;
            }
        }
        return;
    }
    // ---- MFMA projection half: 16 rows, 4 waves K-split ----
    __shared__ float red[4][16][132];
    const int tid = threadIdx.x;
    const bool isA = (blk < 256);
    const float* x; const short* Wf; const float* bias;
    if (isA) { x = P.xa; Wf = P.WfA; bias = P.ba; }
    else { blk -= 256; x = P.xb; Wf = P.WfB; bias = P.bb; }
    const int row0 = blk * 16;
    const int w = tid >> 6;
    const int l = tid & 63;
    const int lr = l & 15;
    const int lk = l >> 4;

    f32x4 acc[8];
#pragma unroll
    for (int c = 0; c < 8; ++c) acc[c] = (f32x4){0.f, 0.f, 0.f, 0.f};

    // hoist ALL x loads (8 independent float4 = 8 outstanding HBM loads)
    const float* xrow = x + (size_t)(row0 + lr) * F_IN;
    float4 xf[8];
#pragma unroll
    for (int ks = 0; ks < 4; ++ks) {
        const int k0 = (w * 4 + ks) * 32 + lk * 8;
        xf[2 * ks]     = *(const float4*)(xrow + k0);
        xf[2 * ks + 1] = *(const float4*)(xrow + k0 + 4);
    }

#pragma unroll
    for (int ks = 0; ks < 4; ++ks) {
        const int t = w * 4 + ks;
        float4 xf0 = xf[2 * ks];
        float4 xf1 = xf[2 * ks + 1];
        short8 afr;
        afr[0] = (short)f2bf(xf0.x); afr[1] = (short)f2bf(xf0.y);
        afr[2] = (short)f2bf(xf0.z); afr[3] = (short)f2bf(xf0.w);
        afr[4] = (short)f2bf(xf1.x); afr[5] = (short)f2bf(xf1.y);
        afr[6] = (short)f2bf(xf1.z); afr[7] = (short)f2bf(xf1.w);
        const short8* wfp = (const short8*)Wf + ((size_t)t * 8 * 64 + l);
#pragma unroll
        for (int c = 0; c < 8; ++c) {
            short8 bfr = wfp[c * 64];
            acc[c] = __builtin_amdgcn_mfma_f32_16x16x32_bf16(afr, bfr, acc[c], 0, 0, 0);
        }
    }

#pragma unroll
    for (int c = 0; c < 8; ++c)
#pragma unroll
        for (int r = 0; r < 4; ++r)
            red[w][lk * 4 + r][c * 16 + lr] = acc[c][r];
    __syncthreads();

#pragma unroll
    for (int q = 0; q < 2; ++q) {
        int fi = tid * 2 + q;          // 0..511
        int r = fi >> 5;               // 0..15
        int c4 = fi & 31;              // float4 col index
        float4 s0 = *(const float4*)&red[0][r][c4 * 4];
        float4 s1 = *(const float4*)&red[1][r][c4 * 4];
        float4 s2 = *(const float4*)&red[2][r][c4 * 4];
        float4 s3 = *(const float4*)&red[3][r][c4 * 4];
        float4 bv = ((const float4*)bias)[c4];
        float ox = fmaxf(s0.x + s1.x + s2.x + s3.x + bv.x, 0.0f);
        float oy = fmaxf(s0.y + s1.y + s2.y + s3.y + bv.y, 0.0f);
        float oz = fmaxf(s0.z + s1.z + s2.z + s3.z + bv.z, 0.0f);
        float ow = fmaxf(s0.w + s1.w + s2.w + s3.w + bv.w, 0.0f);
        if (isA) {
            ushort4v ob;
            ob[0] = f2bf(ox); ob[1] = f2bf(oy); ob[2] = f2bf(oz); ob[3] = f2bf(ow);
            *(ushort4v*)(P.ha_bf + (size_t)(row0 + r) * D_FEAT + c4 * 4) = ob;
        } else {
            float4 o; o.x = ox; o.y = oy; o.z = oz; o.w = ow;
            ((float4*)(P.hb + (size_t)(row0 + r) * D_FEAT))[c4] = o;
        }
    }
}

// 16 bf16-pair gathers accumulated into (ax, ay)
#define GATHER8(CBASE)                                                        \
    {                                                                         \
        int c0 = cols[CBASE],     c1 = cols[CBASE + 1];                       \
        int c2 = cols[CBASE + 2], c3 = cols[CBASE + 3];                       \
        int c4 = cols[CBASE + 4], c5 = cols[CBASE + 5];                       \
        int c6 = cols[CBASE + 6], c7 = cols[CBASE + 7];                       \
        unsigned v0 = s2[(size_t)c0 * 64 + lane];                             \
        unsigned v1 = s2[(size_t)c1 * 64 + lane];                             \
        unsigned v2 = s2[(size_t)c2 * 64 + lane];                             \
        unsigned v3 = s2[(size_t)c3 * 64 + lane];                             \
        unsigned v4 = s2[(size_t)c4 * 64 + lane];                             \
        unsigned v5 = s2[(size_t)c5 * 64 + lane];                             \
        unsigned v6 = s2[(size_t)c6 * 64 + lane];                             \
        unsigned v7 = s2[(size_t)c7 * 64 + lane];                             \
        ax += (bf2f((unsigned short)v0) + bf2f((unsigned short)v1)) +         \
              (bf2f((unsigned short)v2) + bf2f((unsigned short)v3)) +         \
              ((bf2f((unsigned short)v4) + bf2f((unsigned short)v5)) +        \
               (bf2f((unsigned short)v6) + bf2f((unsigned short)v7)));        \
        ay += (bf2f((unsigned short)(v0 >> 16)) + bf2f((unsigned short)(v1 >> 16))) + \
              (bf2f((unsigned short)(v2 >> 16)) + bf2f((unsigned short)(v3 >> 16))) + \
              ((bf2f((unsigned short)(v4 >> 16)) + bf2f((unsigned short)(v5 >> 16))) + \
               (bf2f((unsigned short)(v6 >> 16)) + bf2f((unsigned short)(v7 >> 16)))); \
    }

// ---- K3: u[r] = (1/deg[r] or 0) * sum_{c in B-row r} ha_bf[c] + hb[r] -----
__global__ __launch_bounds__(256) void gather_u_k(Params P) {
    int r = blockIdx.x * 4 + (threadIdx.x >> 6);
    if (r >= NROW) return;
    int lane = threadIdx.x & 63;
    int ncb = P.cnt_ba[r];                 // true B-row degree
    int dgc = P.degc[r];                   // in flight with gathers
    float2 hbv = ((const float2*)P.hb)[(size_t)r * 64 + lane];  // in flight
    int n = ncb > BCAP ? BCAP : ncb;
    const unsigned short* cols = P.buck_ba + (size_t)r * BCAP;
    const unsigned* s2 = (const unsigned*)P.ha_bf;  // 2 bf16 per unsigned
    float ax = 0.0f, ay = 0.0f;
    int e = 0;
    for (; e + 15 < n; e += 16) { GATHER8(e) GATHER8(e + 8) }
    for (; e + 3 < n; e += 4) {
        int c0 = cols[e], c1 = cols[e + 1], c2 = cols[e + 2], c3 = cols[e + 3];
        unsigned v0 = s2[(size_t)c0 * 64 + lane];
        unsigned v1 = s2[(size_t)c1 * 64 + lane];
        unsigned v2 = s2[(size_t)c2 * 64 + lane];
        unsigned v3 = s2[(size_t)c3 * 64 + lane];
        ax += (bf2f((unsigned short)v0) + bf2f((unsigned short)v1)) +
              (bf2f((unsigned short)v2) + bf2f((unsigned short)v3));
        ay += (bf2f((unsigned short)(v0 >> 16)) + bf2f((unsigned short)(v1 >> 16))) +
              (bf2f((unsigned short)(v2 >> 16)) + bf2f((unsigned short)(v3 >> 16)));
    }
    for (; e < n; ++e) {
        unsigned v = s2[(size_t)cols[e] * 64 + lane];
        ax += bf2f((unsigned short)v);
        ay += bf2f((unsigned short)(v >> 16));
    }
    float dgf = (float)(dgc + ncb);
    float inv = dgf > 0.0f ? 1.0f / dgf : 0.0f;
    float ux = ax * inv + hbv.x;
    float uy = ay * inv + hbv.y;
    P.u_bf[(size_t)r * 64 + lane] = (unsigned)f2bf(ux) | ((unsigned)f2bf(uy) << 16);
}

// ---- K4: out[r] = sum_{c in A-row r} u_bf[c]  (f32 output) ----------------
__global__ __launch_bounds__(256) void gather_out_k(Params P) {
    int r = blockIdx.x * 4 + (threadIdx.x >> 6);
    if (r >= NROW) return;
    int lane = threadIdx.x & 63;
    int n = P.cnt_ab[r];
    if (n > BCAP) n = BCAP;
    const unsigned short* cols = P.buck_ab + (size_t)r * BCAP;
    const unsigned* s2 = P.u_bf;
    float ax = 0.0f, ay = 0.0f;
    int e = 0;
    for (; e + 15 < n; e += 16) { GATHER8(e) GATHER8(e + 8) }
    for (; e + 3 < n; e += 4) {
        int c0 = cols[e], c1 = cols[e + 1], c2 = cols[e + 2], c3 = cols[e + 3];
        unsigned v0 = s2[(size_t)c0 * 64 + lane];
        unsigned v1 = s2[(size_t)c1 * 64 + lane];
        unsigned v2 = s2[(size_t)c2 * 64 + lane];
        unsigned v3 = s2[(size_t)c3 * 64 + lane];
        ax += (bf2f((unsigned short)v0) + bf2f((unsigned short)v1)) +
              (bf2f((unsigned short)v2) + bf2f((unsigned short)v3));
        ay += (bf2f((unsigned short)(v0 >> 16)) + bf2f((unsigned short)(v1 >> 16))) +
              (bf2f((unsigned short)(v2 >> 16)) + bf2f((unsigned short)(v3 >> 16)));
    }
    for (; e < n; ++e) {
        unsigned v = s2[(size_t)cols[e] * 64 + lane];
        ax += bf2f((unsigned short)v);
        ay += bf2f((unsigned short)(v >> 16));
    }
    float2 o; o.x = ax; o.y = ay;
    ((float2*)P.out)[(size_t)r * 64 + lane] = o;
}

extern "C" void kernel_launch(void* const* d_in, const int* in_sizes, int n_in,
                              void* d_out, int out_size, void* d_ws, size_t ws_size,
                              hipStream_t stream) {
    const float* x_a = (const float*)d_in[0];
    const float* x_b = (const float*)d_in[1];
    const float* W_a = (const float*)d_in[2];
    const float* b_a = (const float*)d_in[3];
    const float* W_b = (const float*)d_in[4];
    const float* b_b = (const float*)d_in[5];
    const int* ei_ab = (const int*)d_in[6];
    const int* ei_ba = (const int*)d_in[7];

    const int D = in_sizes[3];            // 128
    const int Fa = in_sizes[2] / D;       // 512
    const int Na = in_sizes[0] / Fa;      // 4096
    const int Fb = in_sizes[4] / D;       // 512
    const int Nb = in_sizes[1] / Fb;      // 4096
    const int Eab = in_sizes[6] / 2;      // 131072
    const int Eba = in_sizes[7] / 2;      // 131072

    // ---- workspace layout ----
    char* p = (char*)d_ws;
    unsigned short* ha_bf = (unsigned short*)p; p += (size_t)Na * D * 2;  // 1 MB
    float* h_b = (float*)p; p += (size_t)Nb * D * 4;                      // 2 MB
    unsigned* u_bf = (unsigned*)p; p += (size_t)Nb * (D / 2) * 4;         // 1 MB
    unsigned short* buck_ab = (unsigned short*)p; p += (size_t)Na * BCAP * 2;  // 2 MB
    unsigned short* buck_ba = (unsigned short*)p; p += (size_t)Nb * BCAP * 2;  // 2 MB
    short* WfA = (short*)p; p += (size_t)Fa * D * 2;                      // 128 KB
    short* WfB = (short*)p; p += (size_t)Fb * D * 2;
    int* cnt_ab = (int*)p; p += (size_t)Na * 4;                           // zeroed in K1
    int* cnt_ba = (int*)p; p += (size_t)Nb * 4;
    int* degc   = (int*)p; p += (size_t)Nb * 4;

    Params P;
    P.xa = x_a; P.Wa = W_a; P.ba = b_a;
    P.xb = x_b; P.Wb = W_b; P.bb = b_b;
    P.ab_row = ei_ab; P.ab_col = ei_ab + Eab;
    P.ba_row = ei_ba; P.ba_col = ei_ba + Eba;
    P.WfA = WfA; P.WfB = WfB;
    P.ha_bf = ha_bf; P.hb = h_b; P.u_bf = u_bf;
    P.cnt_ab = cnt_ab; P.cnt_ba = cnt_ba; P.degc = degc;
    P.buck_ab = buck_ab; P.buck_ba = buck_ba;
    P.out = (float*)d_out;
    P.Eab = Eab; P.Eba = Eba;

    // K1: zero counters + W -> fragment layout
    w_prep_k<<<64, 256, 0, stream>>>(P);

    // K2: fat kernel — projections (blocks 0..511) + edge bucketize
    int nblk_g = Na / 16 + Nb / 16;                 // 512
    int nEdgeBlk = (Eab + Eba + 511) / 512;         // 512
    edges_gemm_k<<<nblk_g + nEdgeBlk, 256, 0, stream>>>(P, nblk_g);

    // K3: u = d * (B @ h_a) + h_b   (bf16 out)
    gather_u_k<<<(Nb + 3) / 4, 256, 0, stream>>>(P);

    // K4: out = A @ u
    gather_out_k<<<(Na + 3) / 4, 256, 0, stream>>>(P);
}